// Round 3
// baseline (1001.757 us; speedup 1.0000x reference)
//
#include <hip/hip_runtime.h>
#include <math.h>

#define B_   64
#define NPB  3468            // points (visual words) per batch
#define NPTS (B_ * NPB)      // 221952
#define KC   248
#define D_   64
#define NV   (KC * D_)       // 15872 per-batch vlad elements
#define OCT  8               // norms: chunks per batch
#define N4PB (NPB * D_ / 4)  // 55488 float4s per batch
#define N4CH (N4PB / OCT)    // 6936 float4s per chunk

// ---------------- pass 1a: partial sums of squares per (b, chunk, d)
__global__ __launch_bounds__(256) void norms_part_kernel(const float* __restrict__ feat,
                                                         float* __restrict__ partial) {
    int b = blockIdx.x >> 3, o = blockIdx.x & 7, t = threadIdx.x;
    const float4* f = (const float4*)(feat + (size_t)b * (NPB * D_));
    float ax = 0.f, ay = 0.f, az = 0.f, aw = 0.f;
    for (int j = 0; j < (N4CH + 255) / 256; ++j) {
        int loc = t + j * 256;
        if (loc < N4CH) {
            float4 a = f[o * N4CH + loc];
            ax += a.x * a.x; ay += a.y * a.y; az += a.z * a.z; aw += a.w * a.w;
        }
    }
    // float4 index i4 = o*6936 + t + 256j; dim-group g = (i4 mod 16) = (t + 8o) & 15
    __shared__ float4 red[256];
    red[t] = make_float4(ax, ay, az, aw);
    __syncthreads();
    if (t < 16) {
        int t0 = (t - 8 * o) & 15;   // threads whose group == t
        float sx = 0.f, sy = 0.f, sz = 0.f, sw = 0.f;
        #pragma unroll
        for (int j = 0; j < 16; ++j) {
            float4 a = red[t0 + 16 * j];
            sx += a.x; sy += a.y; sz += a.z; sw += a.w;
        }
        float* dst = partial + ((size_t)(b * OCT + o)) * D_ + 4 * t;
        dst[0] = sx; dst[1] = sy; dst[2] = sz; dst[3] = sw;
    }
}

// ---------------- pass 1b: combine partials -> inv_norm; block 64 -> code half-norms
__global__ __launch_bounds__(256) void norms_combine_kernel(const float* __restrict__ partial,
                                                            const float* __restrict__ codes,
                                                            float* __restrict__ inv_norm,
                                                            float* __restrict__ hn) {
    int t = threadIdx.x;
    if (blockIdx.x == B_) {
        if (t < KC) {
            float s = 0.f;
            #pragma unroll 8
            for (int d = 0; d < D_; ++d) { float c = codes[t * D_ + d]; s += c * c; }
            hn[t] = 0.5f * s;
        }
        return;
    }
    int b = blockIdx.x;
    if (t < D_) {
        float s = 0.f;
        #pragma unroll
        for (int o = 0; o < OCT; ++o) s += partial[((size_t)(b * OCT + o)) * D_ + t];
        inv_norm[b * D_ + t] = 1.f / fmaxf(sqrtf(s), 1e-12f);
    }
}

// ---------------- pass 2: assignment (best code, rinv, bin rank)
__global__ __launch_bounds__(256) void assign_kernel(const float* __restrict__ feat,
                                                     const float* __restrict__ codes,
                                                     const float* __restrict__ inv_norm,
                                                     const float* __restrict__ hn,
                                                     unsigned char* __restrict__ kout,
                                                     float* __restrict__ rinvout,
                                                     unsigned short* __restrict__ rankout,
                                                     int* __restrict__ counts) {
    __shared__ float4 lc[KC * 16];   // 63488 B
    __shared__ float  lhn[KC];
    int t = threadIdx.x;
    const float4* c4 = (const float4*)codes;
    for (int i = t; i < KC * 16; i += 256) lc[i] = c4[i];
    for (int i = t; i < KC; i += 256) lhn[i] = hn[i];
    __syncthreads();

    int base = blockIdx.x * 512;
    int p0 = base + t;
    int p1 = base + 256 + t;
    bool w1 = (p1 < NPTS);
    int p1c = w1 ? p1 : p0;

    int b0 = p0 / NPB;
    int b1 = p1c / NPB;

    float v0[D_], v1[D_];
    float q0 = 0.f, q1 = 0.f;
    {
        const float4* f0 = (const float4*)(feat + (size_t)p0 * D_);
        const float4* n0 = (const float4*)(inv_norm + b0 * D_);
        #pragma unroll
        for (int j = 0; j < 16; ++j) {
            float4 a = f0[j], w = n0[j];
            v0[4*j+0] = a.x * w.x; v0[4*j+1] = a.y * w.y;
            v0[4*j+2] = a.z * w.z; v0[4*j+3] = a.w * w.w;
            q0 += v0[4*j+0]*v0[4*j+0] + v0[4*j+1]*v0[4*j+1]
                + v0[4*j+2]*v0[4*j+2] + v0[4*j+3]*v0[4*j+3];
        }
        const float4* f1 = (const float4*)(feat + (size_t)p1c * D_);
        const float4* n1 = (const float4*)(inv_norm + b1 * D_);
        #pragma unroll
        for (int j = 0; j < 16; ++j) {
            float4 a = f1[j], w = n1[j];
            v1[4*j+0] = a.x * w.x; v1[4*j+1] = a.y * w.y;
            v1[4*j+2] = a.z * w.z; v1[4*j+3] = a.w * w.w;
            q1 += v1[4*j+0]*v1[4*j+0] + v1[4*j+1]*v1[4*j+1]
                + v1[4*j+2]*v1[4*j+2] + v1[4*j+3]*v1[4*j+3];
        }
    }

    float best0 = -3.0e38f, best1 = -3.0e38f;
    int k0 = 0, k1 = 0;
    for (int k = 0; k < KC; ++k) {
        float a0 = 0.f, a1 = 0.f, a2 = 0.f, a3 = 0.f;
        float c0 = 0.f, c1 = 0.f, c2 = 0.f, c3 = 0.f;
        #pragma unroll
        for (int j = 0; j < 16; ++j) {
            float4 c = lc[k * 16 + j];
            a0 += v0[4*j+0] * c.x; a1 += v0[4*j+1] * c.y;
            a2 += v0[4*j+2] * c.z; a3 += v0[4*j+3] * c.w;
            c0 += v1[4*j+0] * c.x; c1 += v1[4*j+1] * c.y;
            c2 += v1[4*j+2] * c.z; c3 += v1[4*j+3] * c.w;
        }
        float s0 = (a0 + a1) + (a2 + a3) - lhn[k];
        float s1 = (c0 + c1) + (c2 + c3) - lhn[k];
        if (s0 > best0) { best0 = s0; k0 = k; }
        if (s1 > best1) { best1 = s1; k1 = k; }
    }

    {
        float rinv0 = 1.f / (sqrtf(fmaxf(q0 - 2.f * best0, 0.f)) + 1e-8f);
        kout[p0] = (unsigned char)k0;
        rinvout[p0] = rinv0;
        int r = atomicAdd(&counts[b0 * KC + k0], 1);
        rankout[p0] = (unsigned short)r;
    }
    if (w1) {
        float rinv1 = 1.f / (sqrtf(fmaxf(q1 - 2.f * best1, 0.f)) + 1e-8f);
        kout[p1] = (unsigned char)k1;
        rinvout[p1] = rinv1;
        int r = atomicAdd(&counts[b1 * KC + k1], 1);
        rankout[p1] = (unsigned short)r;
    }
}

// ---------------- pass 3: per-batch exclusive prefix over 248 bin counts
__global__ __launch_bounds__(256) void prefix_kernel(const int* __restrict__ counts,
                                                     int* __restrict__ base) {
    __shared__ int lcnt[KC];
    __shared__ int lbase[KC];
    int b = blockIdx.x, t = threadIdx.x;
    if (t < KC) lcnt[t] = counts[b * KC + t];
    __syncthreads();
    if (t == 0) {
        int run = 0;
        for (int k = 0; k < KC; ++k) { lbase[k] = run; run += lcnt[k]; }
    }
    __syncthreads();
    if (t < KC) base[b * KC + t] = lbase[t];
}

// ---------------- pass 4: scatter points into sorted bin order
__global__ __launch_bounds__(256) void scatter_kernel(const unsigned char* __restrict__ kout,
                                                      const float* __restrict__ rinvout,
                                                      const unsigned short* __restrict__ rankout,
                                                      const int* __restrict__ base,
                                                      unsigned short* __restrict__ spidx,
                                                      float* __restrict__ srinv) {
    int p = blockIdx.x * 256 + threadIdx.x;
    if (p >= NPTS) return;
    int b = p / NPB;
    int k = (int)kout[p];
    int pos = b * NPB + base[b * KC + k] + (int)rankout[p];
    spidx[pos] = (unsigned short)(p - b * NPB);
    srinv[pos] = rinvout[p];
}

// ---------------- pass 5: atomic-free aggregation; one wave per (b,k), lane=d
__global__ __launch_bounds__(256) void aggregate_kernel(const float* __restrict__ feat,
                                                        const float* __restrict__ codes,
                                                        const float* __restrict__ inv_norm,
                                                        const int* __restrict__ base,
                                                        const int* __restrict__ counts,
                                                        const unsigned short* __restrict__ spidx,
                                                        const float* __restrict__ srinv,
                                                        float* __restrict__ out) {
    int wv = threadIdx.x >> 6, lane = threadIdx.x & 63;
    int b = blockIdx.x / (KC / 4);
    int k = (blockIdx.x % (KC / 4)) * 4 + wv;
    int bk = b * KC + k;
    int s = b * NPB + base[bk];
    int c = counts[bk];
    const float* fb = feat + (size_t)b * (NPB * D_) + lane;

    float acc = 0.f, Sr = 0.f;
    int i = 0;
    for (; i + 2 <= c; i += 2) {
        int  p0 = spidx[s + i],     p1 = spidx[s + i + 1];
        float r0 = srinv[s + i],    r1 = srinv[s + i + 1];
        float x0 = fb[(size_t)p0 * D_];
        float x1 = fb[(size_t)p1 * D_];
        acc = fmaf(x0, r0, acc);
        acc = fmaf(x1, r1, acc);
        Sr += r0 + r1;
    }
    if (i < c) {
        int p0 = spidx[s + i];
        float r0 = srinv[s + i];
        acc = fmaf(fb[(size_t)p0 * D_], r0, acc);
        Sr += r0;
    }
    float val = acc * inv_norm[b * D_ + lane] - codes[k * D_ + lane] * Sr;
    out[(size_t)b * NV + k * D_ + lane] = val;
}

// ---------------- pass 6: per-batch standardize, in place
__global__ __launch_bounds__(1024) void std_kernel(float* __restrict__ v) {
    int b = blockIdx.x, t = threadIdx.x;
    float* row = v + (size_t)b * NV;
    double s = 0.0, ss = 0.0;
    for (int i = t; i < NV; i += 1024) {
        float x = row[i];
        s += (double)x;
        ss += (double)x * (double)x;
    }
    __shared__ double rs[1024], rss[1024];
    rs[t] = s; rss[t] = ss;
    __syncthreads();
    for (int off = 512; off > 0; off >>= 1) {
        if (t < off) { rs[t] += rs[t + off]; rss[t] += rss[t + off]; }
        __syncthreads();
    }
    __shared__ float fmean, fscale;
    if (t == 0) {
        double S = rs[0], SS = rss[0];
        double mean = S / (double)NV;
        double var = (SS - S * S / (double)NV) / (double)(NV - 1);
        double sd = sqrt(var > 0.0 ? var : 0.0);
        fmean = (float)mean;
        fscale = (float)(1.0 / (sd + 1e-8));
    }
    __syncthreads();
    float m = fmean, sc = fscale;
    for (int i = t; i < NV; i += 1024) row[i] = (row[i] - m) * sc;
}

extern "C" void kernel_launch(void* const* d_in, const int* in_sizes, int n_in,
                              void* d_out, int out_size, void* d_ws, size_t ws_size,
                              hipStream_t stream) {
    const float* feat  = (const float*)d_in[0];
    const float* codes = (const float*)d_in[1];
    float* out = (float*)d_out;

    char* ws = (char*)d_ws;
    float* inv_norm      = (float*)(ws);                       // 4096 f
    float* hn            = (float*)(ws + 16384);               // 248 f (pad->17408)
    float* partial       = (float*)(ws + 17408);               // 64*8*64 f = 131072 B
    int*   counts        = (int*)  (ws + 148480);              // 15872 i = 63488 B
    int*   basep         = (int*)  (ws + 211968);              // 15872 i = 63488 B
    unsigned short* rank = (unsigned short*)(ws + 275456);     // 221952 us = 443904 B
    unsigned char* kbuf  = (unsigned char*)(ws + 719360);      // 221952 B
    float* rinvbuf       = (float*)(ws + 941312);              // 221952 f = 887808 B
    unsigned short* spidx= (unsigned short*)(ws + 1829120);    // 443904 B
    float* srinv         = (float*)(ws + 2273024);             // 887808 B  (end ~3.16 MB)

    hipMemsetAsync(counts, 0, B_ * KC * sizeof(int), stream);
    hipLaunchKernelGGL(norms_part_kernel, dim3(B_ * OCT), dim3(256), 0, stream,
                       feat, partial);
    hipLaunchKernelGGL(norms_combine_kernel, dim3(B_ + 1), dim3(256), 0, stream,
                       partial, codes, inv_norm, hn);
    hipLaunchKernelGGL(assign_kernel, dim3((NPTS + 511) / 512), dim3(256), 0, stream,
                       feat, codes, inv_norm, hn, kbuf, rinvbuf, rank, counts);
    hipLaunchKernelGGL(prefix_kernel, dim3(B_), dim3(256), 0, stream, counts, basep);
    hipLaunchKernelGGL(scatter_kernel, dim3((NPTS + 255) / 256), dim3(256), 0, stream,
                       kbuf, rinvbuf, rank, basep, spidx, srinv);
    hipLaunchKernelGGL(aggregate_kernel, dim3(B_ * (KC / 4)), dim3(256), 0, stream,
                       feat, codes, inv_norm, basep, counts, spidx, srinv, out);
    hipLaunchKernelGGL(std_kernel, dim3(B_), dim3(1024), 0, stream, out);
}

// Round 4
// 229.012 us; speedup vs baseline: 4.3743x; 4.3743x over previous
//
#include <hip/hip_runtime.h>
#include <math.h>

#define B_   64
#define NPB  3468            // points (visual words) per batch
#define NPTS (B_ * NPB)      // 221952
#define KC   248
#define D_   64
#define NV   (KC * D_)       // 15872 per-batch vlad elements
#define OCT  8               // norms: chunks per batch
#define N4PB (NPB * D_ / 4)  // 55488 float4s per batch
#define N4CH (N4PB / OCT)    // 6936 float4s per chunk
#define CHPB 55              // aggregation chunks per batch (54*64 + 12)
#define APAD 65

// ---------------- pass 1a: partial sums of squares per (b, chunk, d)
__global__ __launch_bounds__(256) void norms_part_kernel(const float* __restrict__ feat,
                                                         float* __restrict__ partial) {
    int b = blockIdx.x >> 3, o = blockIdx.x & 7, t = threadIdx.x;
    const float4* f = (const float4*)(feat + (size_t)b * (NPB * D_));
    float ax = 0.f, ay = 0.f, az = 0.f, aw = 0.f;
    for (int j = 0; j < (N4CH + 255) / 256; ++j) {
        int loc = t + j * 256;
        if (loc < N4CH) {
            float4 a = f[o * N4CH + loc];
            ax += a.x * a.x; ay += a.y * a.y; az += a.z * a.z; aw += a.w * a.w;
        }
    }
    // float4 index i4 = o*6936 + t + 256j; dim-group g = (i4 mod 16) = (t + 8o) & 15
    __shared__ float4 red[256];
    red[t] = make_float4(ax, ay, az, aw);
    __syncthreads();
    if (t < 16) {
        int t0 = (t - 8 * o) & 15;   // threads whose group == t
        float sx = 0.f, sy = 0.f, sz = 0.f, sw = 0.f;
        #pragma unroll
        for (int j = 0; j < 16; ++j) {
            float4 a = red[t0 + 16 * j];
            sx += a.x; sy += a.y; sz += a.z; sw += a.w;
        }
        float* dst = partial + ((size_t)(b * OCT + o)) * D_ + 4 * t;
        dst[0] = sx; dst[1] = sy; dst[2] = sz; dst[3] = sw;
    }
}

// ---------------- pass 1b: combine partials -> inv_norm; block 64 -> code half-norms
__global__ __launch_bounds__(256) void norms_combine_kernel(const float* __restrict__ partial,
                                                            const float* __restrict__ codes,
                                                            float* __restrict__ inv_norm,
                                                            float* __restrict__ hn) {
    int t = threadIdx.x;
    if (blockIdx.x == B_) {
        if (t < KC) {
            float s = 0.f;
            #pragma unroll 8
            for (int d = 0; d < D_; ++d) { float c = codes[t * D_ + d]; s += c * c; }
            hn[t] = 0.5f * s;
        }
        return;
    }
    int b = blockIdx.x;
    if (t < D_) {
        float s = 0.f;
        #pragma unroll
        for (int o = 0; o < OCT; ++o) s += partial[((size_t)(b * OCT + o)) * D_ + t];
        inv_norm[b * D_ + t] = 1.f / fmaxf(sqrtf(s), 1e-12f);
    }
}

// ---------------- pass 2: assignment (best code, rinv, bin rank)
__global__ __launch_bounds__(256) void assign_kernel(const float* __restrict__ feat,
                                                     const float* __restrict__ codes,
                                                     const float* __restrict__ inv_norm,
                                                     const float* __restrict__ hn,
                                                     unsigned char* __restrict__ kout,
                                                     float* __restrict__ rinvout,
                                                     unsigned short* __restrict__ rankout,
                                                     int* __restrict__ counts) {
    __shared__ float4 lc[KC * 16];   // 63488 B
    __shared__ float  lhn[KC];
    int t = threadIdx.x;
    const float4* c4 = (const float4*)codes;
    for (int i = t; i < KC * 16; i += 256) lc[i] = c4[i];
    for (int i = t; i < KC; i += 256) lhn[i] = hn[i];
    __syncthreads();

    int base = blockIdx.x * 512;
    int p0 = base + t;
    int p1 = base + 256 + t;
    bool w1 = (p1 < NPTS);
    int p1c = w1 ? p1 : p0;

    int b0 = p0 / NPB;
    int b1 = p1c / NPB;

    float v0[D_], v1[D_];
    float q0 = 0.f, q1 = 0.f;
    {
        const float4* f0 = (const float4*)(feat + (size_t)p0 * D_);
        const float4* n0 = (const float4*)(inv_norm + b0 * D_);
        #pragma unroll
        for (int j = 0; j < 16; ++j) {
            float4 a = f0[j], w = n0[j];
            v0[4*j+0] = a.x * w.x; v0[4*j+1] = a.y * w.y;
            v0[4*j+2] = a.z * w.z; v0[4*j+3] = a.w * w.w;
            q0 += v0[4*j+0]*v0[4*j+0] + v0[4*j+1]*v0[4*j+1]
                + v0[4*j+2]*v0[4*j+2] + v0[4*j+3]*v0[4*j+3];
        }
        const float4* f1 = (const float4*)(feat + (size_t)p1c * D_);
        const float4* n1 = (const float4*)(inv_norm + b1 * D_);
        #pragma unroll
        for (int j = 0; j < 16; ++j) {
            float4 a = f1[j], w = n1[j];
            v1[4*j+0] = a.x * w.x; v1[4*j+1] = a.y * w.y;
            v1[4*j+2] = a.z * w.z; v1[4*j+3] = a.w * w.w;
            q1 += v1[4*j+0]*v1[4*j+0] + v1[4*j+1]*v1[4*j+1]
                + v1[4*j+2]*v1[4*j+2] + v1[4*j+3]*v1[4*j+3];
        }
    }

    float best0 = -3.0e38f, best1 = -3.0e38f;
    int k0 = 0, k1 = 0;
    for (int k = 0; k < KC; ++k) {
        float a0 = 0.f, a1 = 0.f, a2 = 0.f, a3 = 0.f;
        float c0 = 0.f, c1 = 0.f, c2 = 0.f, c3 = 0.f;
        #pragma unroll
        for (int j = 0; j < 16; ++j) {
            float4 c = lc[k * 16 + j];
            a0 += v0[4*j+0] * c.x; a1 += v0[4*j+1] * c.y;
            a2 += v0[4*j+2] * c.z; a3 += v0[4*j+3] * c.w;
            c0 += v1[4*j+0] * c.x; c1 += v1[4*j+1] * c.y;
            c2 += v1[4*j+2] * c.z; c3 += v1[4*j+3] * c.w;
        }
        float s0 = (a0 + a1) + (a2 + a3) - lhn[k];
        float s1 = (c0 + c1) + (c2 + c3) - lhn[k];
        if (s0 > best0) { best0 = s0; k0 = k; }
        if (s1 > best1) { best1 = s1; k1 = k; }
    }

    {
        float rinv0 = 1.f / (sqrtf(fmaxf(q0 - 2.f * best0, 0.f)) + 1e-8f);
        kout[p0] = (unsigned char)k0;
        rinvout[p0] = rinv0;
        int r = atomicAdd(&counts[b0 * KC + k0], 1);
        rankout[p0] = (unsigned short)r;
    }
    if (w1) {
        float rinv1 = 1.f / (sqrtf(fmaxf(q1 - 2.f * best1, 0.f)) + 1e-8f);
        kout[p1] = (unsigned char)k1;
        rinvout[p1] = rinv1;
        int r = atomicAdd(&counts[b1 * KC + k1], 1);
        rankout[p1] = (unsigned short)r;
    }
}

// ---------------- pass 3: per-batch exclusive prefix over 248 bin counts
__global__ __launch_bounds__(256) void prefix_kernel(const int* __restrict__ counts,
                                                     int* __restrict__ base) {
    __shared__ int lcnt[KC];
    __shared__ int lbase[KC];
    int b = blockIdx.x, t = threadIdx.x;
    if (t < KC) lcnt[t] = counts[b * KC + t];
    __syncthreads();
    if (t == 0) {
        int run = 0;
        for (int k = 0; k < KC; ++k) { lbase[k] = run; run += lcnt[k]; }
    }
    __syncthreads();
    if (t < KC) base[b * KC + t] = lbase[t];
}

// ---------------- pass 4: scatter points into sorted bin order
__global__ __launch_bounds__(256) void scatter_kernel(const unsigned char* __restrict__ kout,
                                                      const float* __restrict__ rinvout,
                                                      const unsigned short* __restrict__ rankout,
                                                      const int* __restrict__ base,
                                                      unsigned short* __restrict__ spidx,
                                                      float* __restrict__ srinv,
                                                      unsigned char* __restrict__ skbuf) {
    int p = blockIdx.x * 256 + threadIdx.x;
    if (p >= NPTS) return;
    int b = p / NPB;
    int k = (int)kout[p];
    int pos = b * NPB + base[b * KC + k] + (int)rankout[p];
    spidx[pos] = (unsigned short)(p - b * NPB);
    srinv[pos] = rinvout[p];
    skbuf[pos] = (unsigned char)k;
}

// ---------------- pass 5: load-balanced segmented aggregation
// One wave per 64 consecutive sorted positions; flush per-segment partials
// with sparse global atomics (few per chunk). Skew-proof.
__global__ __launch_bounds__(256) void aggregate_kernel(const float* __restrict__ feat,
                                                        const unsigned short* __restrict__ spidx,
                                                        const unsigned char* __restrict__ skbuf,
                                                        const float* __restrict__ srinv,
                                                        float* __restrict__ vacc,
                                                        float* __restrict__ Sacc) {
    int wv = threadIdx.x >> 6, lane = threadIdx.x & 63;
    int chunk = blockIdx.x * 4 + wv;
    if (chunk >= B_ * CHPB) return;
    int b = chunk / CHPB, j = chunk % CHPB;
    int c0 = j * 64;
    int len = NPB - c0; if (len > 64) len = 64;
    int sbase = b * NPB;
    int pos = sbase + c0 + ((lane < len) ? lane : 0);
    int myp = (int)spidx[pos];
    int myk = (int)skbuf[pos];
    float myr = srinv[pos];
    const float* fb = feat + (size_t)sbase * D_ + lane;

    float acc = 0.f, Sr = 0.f;
    int kcur = -1;
    for (int i = 0; i < len; i += 4) {
        int n = len - i; if (n > 4) n = 4;
        float x[4], rr[4];
        int kk[4];
        #pragma unroll
        for (int u = 0; u < 4; ++u) {
            if (u < n) {
                int p = __shfl(myp, i + u);
                kk[u] = __shfl(myk, i + u);
                rr[u] = __shfl(myr, i + u);
                x[u] = fb[(size_t)p * D_];
            }
        }
        for (int u = 0; u < n; ++u) {
            if (kk[u] != kcur) {
                if (kcur >= 0) {
                    atomicAdd(vacc + ((size_t)b * KC + kcur) * D_ + lane, acc);
                    if (lane == 0) atomicAdd(Sacc + b * KC + kcur, Sr);
                }
                kcur = kk[u]; acc = 0.f; Sr = 0.f;
            }
            acc = fmaf(x[u], rr[u], acc);
            Sr += rr[u];
        }
    }
    if (kcur >= 0) {
        atomicAdd(vacc + ((size_t)b * KC + kcur) * D_ + lane, acc);
        if (lane == 0) atomicAdd(Sacc + b * KC + kcur, Sr);
    }
}

// ---------------- pass 6: finalize vlad + per-batch standardize (fused)
__global__ __launch_bounds__(1024) void final_std_kernel(const float* __restrict__ vacc,
                                                         const float* __restrict__ Sacc,
                                                         const float* __restrict__ codes,
                                                         const float* __restrict__ inv_norm,
                                                         float* __restrict__ out) {
    __shared__ float val[KC * APAD];   // 64480 B
    __shared__ float Sl[KC];
    __shared__ float invl[D_];
    __shared__ double rs[1024], rss[1024];
    int b = blockIdx.x, t = threadIdx.x;
    if (t < KC) Sl[t] = Sacc[b * KC + t];
    if (t < D_) invl[t] = inv_norm[b * D_ + t];
    __syncthreads();

    const float* va = vacc + (size_t)b * NV;
    double s = 0.0, ss = 0.0;
    for (int i = t; i < NV; i += 1024) {
        int k = i >> 6, d = i & 63;
        float v = invl[d] * va[i] - codes[i] * Sl[k];
        val[k * APAD + d] = v;
        s += (double)v;
        ss += (double)v * (double)v;
    }
    rs[t] = s; rss[t] = ss;
    __syncthreads();
    for (int off = 512; off > 0; off >>= 1) {
        if (t < off) { rs[t] += rs[t + off]; rss[t] += rss[t + off]; }
        __syncthreads();
    }
    __shared__ float fmean, fscale;
    if (t == 0) {
        double S = rs[0], SS = rss[0];
        double mean = S / (double)NV;
        double var = (SS - S * S / (double)NV) / (double)(NV - 1);
        double sd = sqrt(var > 0.0 ? var : 0.0);
        fmean = (float)mean;
        fscale = (float)(1.0 / (sd + 1e-8));
    }
    __syncthreads();
    float m = fmean, sc = fscale;
    float* row = out + (size_t)b * NV;
    for (int i = t; i < NV; i += 1024) {
        int k = i >> 6, d = i & 63;
        row[i] = (val[k * APAD + d] - m) * sc;
    }
}

extern "C" void kernel_launch(void* const* d_in, const int* in_sizes, int n_in,
                              void* d_out, int out_size, void* d_ws, size_t ws_size,
                              hipStream_t stream) {
    const float* feat  = (const float*)d_in[0];
    const float* codes = (const float*)d_in[1];
    float* out = (float*)d_out;

    char* ws = (char*)d_ws;
    float* inv_norm       = (float*)(ws);                     // 16384 B
    float* hn             = (float*)(ws + 16384);             // -> 17408
    float* partial        = (float*)(ws + 17408);             // 131072 B -> 148480
    // --- zeroed region (one memset): counts, Sacc, vacc ---
    int*   counts         = (int*)  (ws + 148480);            // 63488 B -> 211968
    float* Sacc           = (float*)(ws + 211968);            // 63488 B -> 275456
    float* vacc           = (float*)(ws + 275456);            // 4063232 B -> 4338688
    // ------------------------------------------------------
    int*   basep          = (int*)  (ws + 4338688);           // 63488 B -> 4402176
    unsigned short* rank  = (unsigned short*)(ws + 4402176);  // 443904 B -> 4846080
    unsigned char* kbuf   = (unsigned char*)(ws + 4846080);   // 221952 B -> 5068032
    float* rinvbuf        = (float*)(ws + 5068032);           // 887808 B -> 5955840
    unsigned short* spidx = (unsigned short*)(ws + 5955840);  // 443904 B -> 6399744
    float* srinv          = (float*)(ws + 6399744);           // 887808 B -> 7287552
    unsigned char* skbuf  = (unsigned char*)(ws + 7287552);   // 221952 B -> 7509504

    hipMemsetAsync(ws + 148480, 0, 4338688 - 148480, stream);
    hipLaunchKernelGGL(norms_part_kernel, dim3(B_ * OCT), dim3(256), 0, stream,
                       feat, partial);
    hipLaunchKernelGGL(norms_combine_kernel, dim3(B_ + 1), dim3(256), 0, stream,
                       partial, codes, inv_norm, hn);
    hipLaunchKernelGGL(assign_kernel, dim3((NPTS + 511) / 512), dim3(256), 0, stream,
                       feat, codes, inv_norm, hn, kbuf, rinvbuf, rank, counts);
    hipLaunchKernelGGL(prefix_kernel, dim3(B_), dim3(256), 0, stream, counts, basep);
    hipLaunchKernelGGL(scatter_kernel, dim3((NPTS + 255) / 256), dim3(256), 0, stream,
                       kbuf, rinvbuf, rank, basep, spidx, srinv, skbuf);
    hipLaunchKernelGGL(aggregate_kernel, dim3((B_ * CHPB + 3) / 4), dim3(256), 0, stream,
                       feat, spidx, skbuf, srinv, vacc, Sacc);
    hipLaunchKernelGGL(final_std_kernel, dim3(B_), dim3(1024), 0, stream,
                       vacc, Sacc, codes, inv_norm, out);
}